// Round 1
// baseline (918.464 us; speedup 1.0000x reference)
//
#include <hip/hip_runtime.h>
#include <hip/hip_bf16.h>

typedef _Float16 half8 __attribute__((ext_vector_type(8)));
typedef float f32x4 __attribute__((ext_vector_type(4)));

#define BB 16
#define HH 64
#define WW2 64
#define CC 256

// ---------------------------------------------------------------------------
// Kernel A: per-channel deformable sampling (x-dir and y-dir) + depthwise 5x5
// conv + per-(b,c) channel sums for the gating MLP.
// grid = B*H blocks, 256 threads (thread = channel c), loop over x.
// Outputs stored f16 in NHWC pixel-major layout: [pixel=(b,y,x)][c].
// ---------------------------------------------------------------------------
__global__ __launch_bounds__(256) void k_sample(
    const float* __restrict__ x, const float* __restrict__ off,
    const float* __restrict__ lw,
    _Float16* __restrict__ swb, _Float16* __restrict__ shb, _Float16* __restrict__ cvb,
    float* __restrict__ ssw, float* __restrict__ ssh, float* __restrict__ scv)
{
  const int blk = blockIdx.x;           // b*64 + y
  const int b = blk >> 6, y = blk & 63;
  const int c = threadIdx.x;

  const float* xb = x + (size_t)b * HH * WW2 * CC + c;   // x[b, :, :, c], stride CC

  // depthwise conv weights for this channel
  float wgt[25];
  #pragma unroll
  for (int t = 0; t < 25; t++) wgt[t] = lw[c * 25 + t];

  // sliding 5x5 window registers: win[ky][kx] = x[b, y+ky-2, x+kx-2, c]
  float win[5][5];
  #pragma unroll
  for (int ky = 0; ky < 5; ky++) {
    int yy = y + ky - 2;
    bool yv = (yy >= 0 && yy < HH);
    #pragma unroll
    for (int kx = 0; kx < 5; kx++) {
      int xx = kx - 2;
      win[ky][kx] = (yv && xx >= 0) ? xb[(yy * WW2 + xx) * CC] : 0.f;
    }
  }

  const float* offA = off + (((size_t)b * 512 + c) * HH + y) * WW2;        // dx for sw
  const float* offB = off + (((size_t)b * 512 + 256 + c) * HH + y) * WW2;  // dy for sh
  const float* xrow = xb + y * WW2 * CC;                                   // x[b, y, :, c]
  size_t orow = ((size_t)(b * HH + y) * WW2) * CC + c;

  float asw = 0.f, ash = 0.f, acv = 0.f;

  for (int xi = 0; xi < WW2; xi++) {
    // depthwise conv
    float cv = 0.f;
    #pragma unroll
    for (int ky = 0; ky < 5; ky++)
      #pragma unroll
      for (int kx = 0; kx < 5; kx++) cv += wgt[ky * 5 + kx] * win[ky][kx];

    // sw: 1-D bilinear along x (dy == 0 exactly -> wy = 0 branch vanishes)
    float dx = offA[xi];
    float xs = (float)xi + dx;
    float xf = floorf(xs);
    float wx = xs - xf;
    int xq = (int)xf;
    float v0 = (xq >= 0 && xq < WW2) ? xrow[xq * CC] : 0.f;
    float v1 = (xq + 1 >= 0 && xq + 1 < WW2) ? xrow[(xq + 1) * CC] : 0.f;
    float swv = (1.f - wx) * v0 + wx * v1;

    // sh: 1-D bilinear along y
    float dy = offB[xi];
    float ysv = (float)y + dy;
    float yf = floorf(ysv);
    float wy = ysv - yf;
    int yq = (int)yf;
    float u0 = (yq >= 0 && yq < HH) ? xb[(yq * WW2 + xi) * CC] : 0.f;
    float u1 = (yq + 1 >= 0 && yq + 1 < HH) ? xb[((yq + 1) * WW2 + xi) * CC] : 0.f;
    float shv = (1.f - wy) * u0 + wy * u1;

    size_t oi = orow + (size_t)xi * CC;
    swb[oi] = (_Float16)swv;
    shb[oi] = (_Float16)shv;
    cvb[oi] = (_Float16)cv;
    asw += swv; ash += shv; acv += cv;

    // slide window right
    if (xi < WW2 - 1) {
      #pragma unroll
      for (int ky = 0; ky < 5; ky++) {
        #pragma unroll
        for (int kx = 0; kx < 4; kx++) win[ky][kx] = win[ky][kx + 1];
        int yy = y + ky - 2;
        int xx = xi + 3;
        win[ky][4] = (yy >= 0 && yy < HH && xx < WW2) ? xb[(yy * WW2 + xx) * CC] : 0.f;
      }
    }
  }

  atomicAdd(&ssw[b * CC + c], asw);
  atomicAdd(&ssh[b * CC + c], ash);
  atomicAdd(&scv[b * CC + c], acv);
}

// ---------------------------------------------------------------------------
// Kernel B: gating MLP. grid = B blocks, 256 threads.
// avg[b,o] = (sum_c ssw*Ww[o,c] + sum_c ssh*Wh[o,c] + scv[o]) / (H*W) + bw+bh+blc
// t = GELU(avg @ fc1^T + b1);  g = t @ fc2^T + b2;  a[j,b,c] = softmax_j g[b,3c+j]
// ---------------------------------------------------------------------------
__global__ __launch_bounds__(256) void k_gate(
    const float* __restrict__ ssw, const float* __restrict__ ssh, const float* __restrict__ scv,
    const float* __restrict__ Ww, const float* __restrict__ bw,
    const float* __restrict__ Wh, const float* __restrict__ bh,
    const float* __restrict__ blc,
    const float* __restrict__ fc1w, const float* __restrict__ fc1b,
    const float* __restrict__ fc2w, const float* __restrict__ fc2b,
    float* __restrict__ gate)
{
  __shared__ float sswl[CC], sshl[CC], avgl[CC], tl[64];
  const int b = blockIdx.x, tid = threadIdx.x;
  sswl[tid] = ssw[b * CC + tid];
  sshl[tid] = ssh[b * CC + tid];
  __syncthreads();

  float acc = scv[b * CC + tid];
  for (int c = 0; c < CC; c++)
    acc += sswl[c] * Ww[tid * CC + c] + sshl[c] * Wh[tid * CC + c];
  avgl[tid] = acc * (1.f / (HH * WW2)) + bw[tid] + bh[tid] + blc[tid];
  __syncthreads();

  if (tid < 64) {
    float a = fc1b[tid];
    for (int o = 0; o < CC; o++) a += avgl[o] * fc1w[tid * CC + o];
    tl[tid] = 0.5f * a * (1.f + erff(a * 0.70710678118654752f));  // exact GELU
  }
  __syncthreads();

  float g[3];
  #pragma unroll
  for (int j = 0; j < 3; j++) {
    float a = fc2b[tid * 3 + j];
    for (int k = 0; k < 64; k++) a += tl[k] * fc2w[(tid * 3 + j) * 64 + k];
    g[j] = a;
  }
  float m = fmaxf(g[0], fmaxf(g[1], g[2]));
  float e0 = expf(g[0] - m), e1 = expf(g[1] - m), e2 = expf(g[2] - m);
  float inv = 1.f / (e0 + e1 + e2);
  gate[(0 * BB + b) * CC + tid] = e0 * inv;
  gate[(1 * BB + b) * CC + tid] = e1 * inv;
  gate[(2 * BB + b) * CC + tid] = e2 * inv;
}

// ---------------------------------------------------------------------------
// Kernel P: build per-batch scaled concatenated weight B'[b][n][k] (f16),
// k<256: a0*Ww[n][k], k>=256: a1*Wh[n][k]; plus combined bias.
// grid = B*C blocks (one per (b,n)), 256 threads.
// ---------------------------------------------------------------------------
__global__ __launch_bounds__(256) void k_prep(
    const float* __restrict__ gate,
    const float* __restrict__ Ww, const float* __restrict__ Wh,
    const float* __restrict__ bw, const float* __restrict__ bh,
    const float* __restrict__ blc,
    _Float16* __restrict__ Bp, float* __restrict__ bcomb)
{
  const int id = blockIdx.x;       // b*256 + n
  const int b = id >> 8, n = id & 255;
  const int k = threadIdx.x;
  float a0 = gate[(0 * BB + b) * CC + n];
  float a1 = gate[(1 * BB + b) * CC + n];
  float a2 = gate[(2 * BB + b) * CC + n];
  size_t base = (size_t)id * 512;
  Bp[base + k]       = (_Float16)(a0 * Ww[n * CC + k]);
  Bp[base + 256 + k] = (_Float16)(a1 * Wh[n * CC + k]);
  if (k == 0) bcomb[id] = a0 * bw[n] + a1 * bh[n] + a2 * blc[n];
}

// proj -> f16 copy (layout [p][o] row-major, i.e. B operand as [n][k])
__global__ __launch_bounds__(256) void k_cvt(const float* __restrict__ pw,
                                             _Float16* __restrict__ pf)
{
  int i = blockIdx.x * 256 + threadIdx.x;
  pf[i] = (_Float16)pw[i];
}

// ---------------------------------------------------------------------------
// Kernel C1: combined = A_cat[sw|sh] @ B'[b] + bcomb + a2*conv   (K=512 GEMM)
// Direct-from-global MFMA (no LDS): A rows [row][k], B rows [n][k], both give
// 16B contiguous per-lane fragment loads. Block = 64 pixel rows x 256 cols,
// 4 waves (wave = 64-col slice). Writes combined f16 IN PLACE into the conv
// buffer (each (row,col) element is read+written by exactly one lane).
// ---------------------------------------------------------------------------
__global__ __launch_bounds__(256) void k_gemm1(
    const _Float16* __restrict__ swb, const _Float16* __restrict__ shb,
    const _Float16* __restrict__ Bp, const float* __restrict__ bcomb,
    const float* __restrict__ a2g, _Float16* cvcomb)
{
  const int blk = blockIdx.x;
  const int r0 = blk * 64;
  const int b = blk >> 6;           // 64 blocks per batch (4096 px / 64)
  const int tid = threadIdx.x;
  const int wid = tid >> 6, l = tid & 63;
  const int n0 = wid * 64;
  const int lr = l & 15;
  const int kg = (l >> 4) * 8;

  const _Float16* ap0 = swb + (size_t)(r0 + lr) * CC + kg;
  const _Float16* ap1 = shb + (size_t)(r0 + lr) * CC + kg;
  const _Float16* bp  = Bp + ((size_t)b * CC + n0 + lr) * 512 + kg;

  f32x4 acc[4][4];
  #pragma unroll
  for (int mi = 0; mi < 4; mi++)
    #pragma unroll
    for (int ni = 0; ni < 4; ni++) acc[mi][ni] = (f32x4){0.f, 0.f, 0.f, 0.f};

  #pragma unroll
  for (int ks = 0; ks < 16; ks++) {
    half8 a[4], bb[4];
    #pragma unroll
    for (int mi = 0; mi < 4; mi++) {
      const _Float16* s = (ks < 8) ? (ap0 + (size_t)mi * 16 * CC + ks * 32)
                                   : (ap1 + (size_t)mi * 16 * CC + (ks - 8) * 32);
      a[mi] = *(const half8*)s;
    }
    #pragma unroll
    for (int ni = 0; ni < 4; ni++)
      bb[ni] = *(const half8*)(bp + (size_t)ni * 16 * 512 + ks * 32);
    #pragma unroll
    for (int mi = 0; mi < 4; mi++)
      #pragma unroll
      for (int ni = 0; ni < 4; ni++)
        acc[mi][ni] = __builtin_amdgcn_mfma_f32_16x16x32_f16(a[mi], bb[ni], acc[mi][ni], 0, 0, 0);
  }

  const int jr = (l >> 4) * 4;
  #pragma unroll
  for (int ni = 0; ni < 4; ni++) {
    int col = n0 + ni * 16 + lr;
    float bc = bcomb[b * CC + col];
    float a2 = a2g[b * CC + col];
    #pragma unroll
    for (int mi = 0; mi < 4; mi++) {
      #pragma unroll
      for (int j = 0; j < 4; j++) {
        size_t idx = (size_t)(r0 + mi * 16 + jr + j) * CC + col;
        float v = acc[mi][ni][j] + bc + a2 * (float)cvcomb[idx];
        cvcomb[idx] = (_Float16)v;
      }
    }
  }
}

// ---------------------------------------------------------------------------
// Kernel C2: out = combined @ proj^T + proj_b   (K=256 GEMM, f32 out)
// ---------------------------------------------------------------------------
__global__ __launch_bounds__(256) void k_gemm2(
    const _Float16* __restrict__ comb, const _Float16* __restrict__ pf,
    const float* __restrict__ pb, float* __restrict__ out)
{
  const int blk = blockIdx.x;
  const int r0 = blk * 64;
  const int tid = threadIdx.x;
  const int wid = tid >> 6, l = tid & 63;
  const int n0 = wid * 64;
  const int lr = l & 15;
  const int kg = (l >> 4) * 8;

  const _Float16* ap = comb + (size_t)(r0 + lr) * CC + kg;
  const _Float16* bp = pf + (size_t)(n0 + lr) * CC + kg;

  f32x4 acc[4][4];
  #pragma unroll
  for (int mi = 0; mi < 4; mi++)
    #pragma unroll
    for (int ni = 0; ni < 4; ni++) acc[mi][ni] = (f32x4){0.f, 0.f, 0.f, 0.f};

  #pragma unroll
  for (int ks = 0; ks < 8; ks++) {
    half8 a[4], bb[4];
    #pragma unroll
    for (int mi = 0; mi < 4; mi++)
      a[mi] = *(const half8*)(ap + (size_t)mi * 16 * CC + ks * 32);
    #pragma unroll
    for (int ni = 0; ni < 4; ni++)
      bb[ni] = *(const half8*)(bp + (size_t)ni * 16 * CC + ks * 32);
    #pragma unroll
    for (int mi = 0; mi < 4; mi++)
      #pragma unroll
      for (int ni = 0; ni < 4; ni++)
        acc[mi][ni] = __builtin_amdgcn_mfma_f32_16x16x32_f16(a[mi], bb[ni], acc[mi][ni], 0, 0, 0);
  }

  const int jr = (l >> 4) * 4;
  #pragma unroll
  for (int ni = 0; ni < 4; ni++) {
    int col = n0 + ni * 16 + lr;
    float bias = pb[col];
    #pragma unroll
    for (int mi = 0; mi < 4; mi++) {
      #pragma unroll
      for (int j = 0; j < 4; j++) {
        size_t idx = (size_t)(r0 + mi * 16 + jr + j) * CC + col;
        out[idx] = acc[mi][ni][j] + bias;
      }
    }
  }
}

// ---------------------------------------------------------------------------
extern "C" void kernel_launch(void* const* d_in, const int* in_sizes, int n_in,
                              void* d_out, int out_size, void* d_ws, size_t ws_size,
                              hipStream_t stream)
{
  const float* x    = (const float*)d_in[0];
  const float* off  = (const float*)d_in[1];
  const float* Ww   = (const float*)d_in[2];
  const float* bw   = (const float*)d_in[3];
  const float* Wh   = (const float*)d_in[4];
  const float* bh   = (const float*)d_in[5];
  const float* lw   = (const float*)d_in[6];
  const float* blc  = (const float*)d_in[7];
  const float* fc1w = (const float*)d_in[8];
  const float* fc1b = (const float*)d_in[9];
  const float* fc2w = (const float*)d_in[10];
  const float* fc2b = (const float*)d_in[11];
  const float* pw   = (const float*)d_in[12];
  const float* pb   = (const float*)d_in[13];
  float* out = (float*)d_out;

  char* ws = (char*)d_ws;
  // workspace layout (bytes); total ~100.2 MB
  _Float16* swb = (_Float16*)(ws + 0);            // 33,554,432
  _Float16* shb = (_Float16*)(ws + 33554432);     // 33,554,432
  _Float16* cvb = (_Float16*)(ws + 67108864);     // 33,554,432 (conv, then combined in-place)
  _Float16* Bp  = (_Float16*)(ws + 100663296);    //  4,194,304
  _Float16* pf  = (_Float16*)(ws + 104857600);    //    131,072
  float* sums   = (float*)(ws + 104988672);       //     49,152 (ssw|ssh|scv)
  float* gate   = (float*)(ws + 105037824);       //     49,152
  float* bcomb  = (float*)(ws + 105086976);       //     16,384
  float* ssw = sums, *ssh = sums + 4096, *scv = sums + 8192;

  hipMemsetAsync(sums, 0, 3 * 4096 * sizeof(float), stream);
  k_sample<<<BB * HH, 256, 0, stream>>>(x, off, lw, swb, shb, cvb, ssw, ssh, scv);
  k_gate<<<BB, 256, 0, stream>>>(ssw, ssh, scv, Ww, bw, Wh, bh, blc,
                                 fc1w, fc1b, fc2w, fc2b, gate);
  k_prep<<<BB * CC, 256, 0, stream>>>(gate, Ww, Wh, bw, bh, blc, Bp, bcomb);
  k_cvt<<<CC, 256, 0, stream>>>(pw, pf);
  k_gemm1<<<1024, 256, 0, stream>>>(swb, shb, Bp, bcomb, gate + 2 * BB * CC, cvb);
  k_gemm2<<<1024, 256, 0, stream>>>(cvb, pf, pb, out);
}

// Round 2
// 327.944 us; speedup vs baseline: 2.8007x; 2.8007x over previous
//
#include <hip/hip_runtime.h>
#include <hip/hip_bf16.h>

typedef _Float16 half4_t __attribute__((ext_vector_type(4)));
typedef _Float16 half8 __attribute__((ext_vector_type(8)));
typedef float f32x4 __attribute__((ext_vector_type(4)));

#define BB 16
#define HH 64
#define WW2 64
#define CC 256

// ---------------------------------------------------------------------------
// Kernel T: transpose the y-offset half of `off` into offBT[b][xi][y][c] f16.
// Block handles (b, s-tile of 256, ch-tile of 8). Reads coalesced (lane = s),
// each thread packs 8 channels -> one 16B store. XCD swizzle keeps the 4
// line-sharing ch-tiles on one XCD so L2 merges the partial-line writes.
// ---------------------------------------------------------------------------
__global__ __launch_bounds__(256) void k_toffB(const float* __restrict__ off,
                                               _Float16* __restrict__ offBT)
{
  const int work = (blockIdx.x & 7) * 1024 + (blockIdx.x >> 3);  // 8192 blocks
  const int cht = work & 31;
  const int st = (work >> 5) & 15;
  const int b = work >> 9;
  const int t = threadIdx.x;
  const int s = st * 256 + t;          // spatial index y*64+xi
  const int ch0 = 256 + cht * 8;       // y-offset channels live at [256,512)

  const float* src = off + ((size_t)b * 512 + ch0) * 4096 + s;
  half8 hv;
  #pragma unroll
  for (int r = 0; r < 8; r++) hv[r] = (_Float16)src[(size_t)r * 4096];
  const int y = s >> 6, xi = s & 63;
  *(half8*)(offBT + (((size_t)b * 64 + xi) * 64 + y) * 256 + cht * 8) = hv;
}

// ---------------------------------------------------------------------------
// Kernel R: sw sampling + depthwise 5x5 conv. Block = (b,y), thread = channel.
// x row staged f16 in LDS [xi][c] (gathers <=2-way bank, free); offset tile
// staged f16 in LDS [c][66] via coalesced float4 reads. Conv reads stay
// f32-from-global (coalesced, L2-reused across y-adjacent blocks on same XCD).
// ---------------------------------------------------------------------------
__global__ __launch_bounds__(256) void k_row(
    const float* __restrict__ x, const float* __restrict__ off,
    const float* __restrict__ lw,
    _Float16* __restrict__ swb, _Float16* __restrict__ cvb,
    float* __restrict__ ssw, float* __restrict__ scv)
{
  __shared__ _Float16 xr[WW2 * CC];     // [xi][c]
  __shared__ _Float16 oa[CC * 66];      // [c][xi], pad 66 -> 2-way max

  const int work = (blockIdx.x & 7) * 128 + (blockIdx.x >> 3);  // 1024 blocks
  const int b = work >> 6, y = work & 63;
  const int t = threadIdx.x;
  const int c = t;
  const int l = t & 63, w = t >> 6;

  // stage x row -> xr (coalesced float4, f16 convert)
  const float* xrow_src = x + (size_t)(b * HH + y) * WW2 * CC;
  #pragma unroll
  for (int p = 0; p < 16; p++) {
    int i = p * 1024 + t * 4;
    float4 v = *(const float4*)(xrow_src + i);
    half4_t h = {(_Float16)v.x, (_Float16)v.y, (_Float16)v.z, (_Float16)v.w};
    *(half4_t*)(xr + i) = h;
  }
  // stage offA tile: per pass a wave reads 4 channel-rows x 16 float4 (full lines)
  {
    const int cc0 = w * 4 + (l >> 4);
    const int x4 = (l & 15) * 4;
    #pragma unroll
    for (int p = 0; p < 16; p++) {
      int cc = p * 16 + cc0;
      float4 v = *(const float4*)(off + (((size_t)b * 512 + cc) * HH + y) * WW2 + x4);
      oa[cc * 66 + x4 + 0] = (_Float16)v.x;
      oa[cc * 66 + x4 + 1] = (_Float16)v.y;
      oa[cc * 66 + x4 + 2] = (_Float16)v.z;
      oa[cc * 66 + x4 + 3] = (_Float16)v.w;
    }
  }

  // depthwise conv weights + 5x5 sliding window (f32 global, coalesced)
  float wgt[25];
  #pragma unroll
  for (int q = 0; q < 25; q++) wgt[q] = lw[c * 25 + q];
  const float* xb = x + (size_t)b * HH * WW2 * CC + c;
  float win[5][5];
  #pragma unroll
  for (int ky = 0; ky < 5; ky++) {
    int yy = y + ky - 2;
    bool yv = (yy >= 0 && yy < HH);
    #pragma unroll
    for (int kx = 0; kx < 5; kx++) {
      int xx = kx - 2;
      win[ky][kx] = (yv && xx >= 0) ? xb[(yy * WW2 + xx) * CC] : 0.f;
    }
  }
  __syncthreads();

  size_t orow = (size_t)(b * HH + y) * WW2 * CC + c;
  float asw = 0.f, acv = 0.f;

  for (int xi = 0; xi < WW2; xi++) {
    float cv = 0.f;
    #pragma unroll
    for (int ky = 0; ky < 5; ky++)
      #pragma unroll
      for (int kx = 0; kx < 5; kx++) cv += wgt[ky * 5 + kx] * win[ky][kx];

    float dx = (float)oa[c * 66 + xi];
    float xs = (float)xi + dx;
    float xf = floorf(xs);
    float wx = xs - xf;
    int xq = (int)xf;
    float v0 = (xq >= 0 && xq < WW2) ? (float)xr[xq * CC + c] : 0.f;
    float v1 = (xq + 1 >= 0 && xq + 1 < WW2) ? (float)xr[(xq + 1) * CC + c] : 0.f;
    float swv = (1.f - wx) * v0 + wx * v1;

    size_t oi = orow + (size_t)xi * CC;
    swb[oi] = (_Float16)swv;
    cvb[oi] = (_Float16)cv;
    asw += swv; acv += cv;

    if (xi < WW2 - 1) {
      #pragma unroll
      for (int ky = 0; ky < 5; ky++) {
        #pragma unroll
        for (int kx = 0; kx < 4; kx++) win[ky][kx] = win[ky][kx + 1];
        int yy = y + ky - 2;
        int xx = xi + 3;
        win[ky][4] = (yy >= 0 && yy < HH && xx < WW2) ? xb[(yy * WW2 + xx) * CC] : 0.f;
      }
    }
  }

  atomicAdd(&ssw[b * CC + c], asw);
  atomicAdd(&scv[b * CC + c], acv);
}

// ---------------------------------------------------------------------------
// Kernel C: sh sampling. Block = (b, xi), thread = channel. x column staged
// f16 in LDS [y][c]; offsets read coalesced from offBT.
// ---------------------------------------------------------------------------
__global__ __launch_bounds__(256) void k_col(
    const float* __restrict__ x, const _Float16* __restrict__ offBT,
    _Float16* __restrict__ shb, float* __restrict__ ssh)
{
  __shared__ _Float16 xc[HH * CC];      // [y][c]
  const int work = (blockIdx.x & 7) * 128 + (blockIdx.x >> 3);  // 1024 blocks
  const int b = work >> 6, xi = work & 63;
  const int t = threadIdx.x;
  const int c = t;

  #pragma unroll
  for (int p = 0; p < 16; p++) {
    int yy = p * 4 + (t >> 6);
    int c4 = (t & 63) * 4;
    float4 v = *(const float4*)(x + ((size_t)(b * HH + yy) * WW2 + xi) * CC + c4);
    half4_t h = {(_Float16)v.x, (_Float16)v.y, (_Float16)v.z, (_Float16)v.w};
    *(half4_t*)(xc + yy * CC + c4) = h;
  }
  __syncthreads();

  const _Float16* obt = offBT + ((size_t)(b * WW2 + xi) * HH) * CC + c;
  float ash = 0.f;
  for (int yy = 0; yy < HH; yy++) {
    float dy = (float)obt[yy * CC];
    float ys = (float)yy + dy;
    float yf = floorf(ys);
    float wy = ys - yf;
    int yq = (int)yf;
    float u0 = (yq >= 0 && yq < HH) ? (float)xc[yq * CC + c] : 0.f;
    float u1 = (yq + 1 >= 0 && yq + 1 < HH) ? (float)xc[(yq + 1) * CC + c] : 0.f;
    float shv = (1.f - wy) * u0 + wy * u1;
    shb[((size_t)(b * HH + yy) * WW2 + xi) * CC + c] = (_Float16)shv;
    ash += shv;
  }
  atomicAdd(&ssh[b * CC + c], ash);
}

// ---------------------------------------------------------------------------
// Kernel B: gating MLP (unchanged from validated round 0).
// ---------------------------------------------------------------------------
__global__ __launch_bounds__(256) void k_gate(
    const float* __restrict__ ssw, const float* __restrict__ ssh, const float* __restrict__ scv,
    const float* __restrict__ Ww, const float* __restrict__ bw,
    const float* __restrict__ Wh, const float* __restrict__ bh,
    const float* __restrict__ blc,
    const float* __restrict__ fc1w, const float* __restrict__ fc1b,
    const float* __restrict__ fc2w, const float* __restrict__ fc2b,
    float* __restrict__ gate)
{
  __shared__ float sswl[CC], sshl[CC], avgl[CC], tl[64];
  const int b = blockIdx.x, tid = threadIdx.x;
  sswl[tid] = ssw[b * CC + tid];
  sshl[tid] = ssh[b * CC + tid];
  __syncthreads();

  float acc = scv[b * CC + tid];
  for (int c = 0; c < CC; c++)
    acc += sswl[c] * Ww[tid * CC + c] + sshl[c] * Wh[tid * CC + c];
  avgl[tid] = acc * (1.f / (HH * WW2)) + bw[tid] + bh[tid] + blc[tid];
  __syncthreads();

  if (tid < 64) {
    float a = fc1b[tid];
    for (int o = 0; o < CC; o++) a += avgl[o] * fc1w[tid * CC + o];
    tl[tid] = 0.5f * a * (1.f + erff(a * 0.70710678118654752f));
  }
  __syncthreads();

  float g[3];
  #pragma unroll
  for (int j = 0; j < 3; j++) {
    float a = fc2b[tid * 3 + j];
    for (int k = 0; k < 64; k++) a += tl[k] * fc2w[(tid * 3 + j) * 64 + k];
    g[j] = a;
  }
  float m = fmaxf(g[0], fmaxf(g[1], g[2]));
  float e0 = expf(g[0] - m), e1 = expf(g[1] - m), e2 = expf(g[2] - m);
  float inv = 1.f / (e0 + e1 + e2);
  gate[(0 * BB + b) * CC + tid] = e0 * inv;
  gate[(1 * BB + b) * CC + tid] = e1 * inv;
  gate[(2 * BB + b) * CC + tid] = e2 * inv;
}

// ---------------------------------------------------------------------------
// Kernel P: per-batch scaled concatenated weight B'[b][n][k] + combined bias.
// ---------------------------------------------------------------------------
__global__ __launch_bounds__(256) void k_prep(
    const float* __restrict__ gate,
    const float* __restrict__ Ww, const float* __restrict__ Wh,
    const float* __restrict__ bw, const float* __restrict__ bh,
    const float* __restrict__ blc,
    _Float16* __restrict__ Bp, float* __restrict__ bcomb)
{
  const int id = blockIdx.x;       // b*256 + n
  const int b = id >> 8, n = id & 255;
  const int k = threadIdx.x;
  float a0 = gate[(0 * BB + b) * CC + n];
  float a1 = gate[(1 * BB + b) * CC + n];
  float a2 = gate[(2 * BB + b) * CC + n];
  size_t base = (size_t)id * 512;
  Bp[base + k]       = (_Float16)(a0 * Ww[n * CC + k]);
  Bp[base + 256 + k] = (_Float16)(a1 * Wh[n * CC + k]);
  if (k == 0) bcomb[id] = a0 * bw[n] + a1 * bh[n] + a2 * blc[n];
}

__global__ __launch_bounds__(256) void k_cvt(const float* __restrict__ pw,
                                             _Float16* __restrict__ pf)
{
  int i = blockIdx.x * 256 + threadIdx.x;
  pf[i] = (_Float16)pw[i];
}

// ---------------------------------------------------------------------------
// Kernel C1: combined = [sw|sh] @ B'[b] + bcomb + a2*conv (K=512), in-place
// into the conv buffer. Direct-from-global MFMA fragments (full-line loads).
// ---------------------------------------------------------------------------
__global__ __launch_bounds__(256) void k_gemm1(
    const _Float16* __restrict__ swb, const _Float16* __restrict__ shb,
    const _Float16* __restrict__ Bp, const float* __restrict__ bcomb,
    const float* __restrict__ a2g, _Float16* cvcomb)
{
  const int work = (blockIdx.x & 7) * 128 + (blockIdx.x >> 3);  // 1024 blocks
  const int r0 = work * 64;
  const int b = work >> 6;
  const int tid = threadIdx.x;
  const int wid = tid >> 6, l = tid & 63;
  const int n0 = wid * 64;
  const int lr = l & 15;
  const int kg = (l >> 4) * 8;

  const _Float16* ap0 = swb + (size_t)(r0 + lr) * CC + kg;
  const _Float16* ap1 = shb + (size_t)(r0 + lr) * CC + kg;
  const _Float16* bp  = Bp + ((size_t)b * CC + n0 + lr) * 512 + kg;

  f32x4 acc[4][4];
  #pragma unroll
  for (int mi = 0; mi < 4; mi++)
    #pragma unroll
    for (int ni = 0; ni < 4; ni++) acc[mi][ni] = (f32x4){0.f, 0.f, 0.f, 0.f};

  #pragma unroll
  for (int ks = 0; ks < 16; ks++) {
    half8 a[4], bb[4];
    #pragma unroll
    for (int mi = 0; mi < 4; mi++) {
      const _Float16* s = (ks < 8) ? (ap0 + (size_t)mi * 16 * CC + ks * 32)
                                   : (ap1 + (size_t)mi * 16 * CC + (ks - 8) * 32);
      a[mi] = *(const half8*)s;
    }
    #pragma unroll
    for (int ni = 0; ni < 4; ni++)
      bb[ni] = *(const half8*)(bp + (size_t)ni * 16 * 512 + ks * 32);
    #pragma unroll
    for (int mi = 0; mi < 4; mi++)
      #pragma unroll
      for (int ni = 0; ni < 4; ni++)
        acc[mi][ni] = __builtin_amdgcn_mfma_f32_16x16x32_f16(a[mi], bb[ni], acc[mi][ni], 0, 0, 0);
  }

  const int jr = (l >> 4) * 4;
  #pragma unroll
  for (int ni = 0; ni < 4; ni++) {
    int col = n0 + ni * 16 + lr;
    float bc = bcomb[b * CC + col];
    float a2 = a2g[b * CC + col];
    #pragma unroll
    for (int mi = 0; mi < 4; mi++) {
      #pragma unroll
      for (int j = 0; j < 4; j++) {
        size_t idx = (size_t)(r0 + mi * 16 + jr + j) * CC + col;
        float v = acc[mi][ni][j] + bc + a2 * (float)cvcomb[idx];
        cvcomb[idx] = (_Float16)v;
      }
    }
  }
}

// ---------------------------------------------------------------------------
// Kernel C2: out = combined @ proj^T + proj_b (K=256, f32 out).
// ---------------------------------------------------------------------------
__global__ __launch_bounds__(256) void k_gemm2(
    const _Float16* __restrict__ comb, const _Float16* __restrict__ pf,
    const float* __restrict__ pb, float* __restrict__ out)
{
  const int blk = blockIdx.x;
  const int r0 = blk * 64;
  const int tid = threadIdx.x;
  const int wid = tid >> 6, l = tid & 63;
  const int n0 = wid * 64;
  const int lr = l & 15;
  const int kg = (l >> 4) * 8;

  const _Float16* ap = comb + (size_t)(r0 + lr) * CC + kg;
  const _Float16* bp = pf + (size_t)(n0 + lr) * CC + kg;

  f32x4 acc[4][4];
  #pragma unroll
  for (int mi = 0; mi < 4; mi++)
    #pragma unroll
    for (int ni = 0; ni < 4; ni++) acc[mi][ni] = (f32x4){0.f, 0.f, 0.f, 0.f};

  #pragma unroll
  for (int ks = 0; ks < 8; ks++) {
    half8 a[4], bb[4];
    #pragma unroll
    for (int mi = 0; mi < 4; mi++)
      a[mi] = *(const half8*)(ap + (size_t)mi * 16 * CC + ks * 32);
    #pragma unroll
    for (int ni = 0; ni < 4; ni++)
      bb[ni] = *(const half8*)(bp + (size_t)ni * 16 * CC + ks * 32);
    #pragma unroll
    for (int mi = 0; mi < 4; mi++)
      #pragma unroll
      for (int ni = 0; ni < 4; ni++)
        acc[mi][ni] = __builtin_amdgcn_mfma_f32_16x16x32_f16(a[mi], bb[ni], acc[mi][ni], 0, 0, 0);
  }

  const int jr = (l >> 4) * 4;
  #pragma unroll
  for (int ni = 0; ni < 4; ni++) {
    int col = n0 + ni * 16 + lr;
    float bias = pb[col];
    #pragma unroll
    for (int mi = 0; mi < 4; mi++) {
      #pragma unroll
      for (int j = 0; j < 4; j++) {
        size_t idx = (size_t)(r0 + mi * 16 + jr + j) * CC + col;
        out[idx] = acc[mi][ni][j] + bias;
      }
    }
  }
}

// ---------------------------------------------------------------------------
extern "C" void kernel_launch(void* const* d_in, const int* in_sizes, int n_in,
                              void* d_out, int out_size, void* d_ws, size_t ws_size,
                              hipStream_t stream)
{
  const float* x    = (const float*)d_in[0];
  const float* off  = (const float*)d_in[1];
  const float* Ww   = (const float*)d_in[2];
  const float* bw   = (const float*)d_in[3];
  const float* Wh   = (const float*)d_in[4];
  const float* bh   = (const float*)d_in[5];
  const float* lw   = (const float*)d_in[6];
  const float* blc  = (const float*)d_in[7];
  const float* fc1w = (const float*)d_in[8];
  const float* fc1b = (const float*)d_in[9];
  const float* fc2w = (const float*)d_in[10];
  const float* fc2b = (const float*)d_in[11];
  const float* pw   = (const float*)d_in[12];
  const float* pb   = (const float*)d_in[13];
  float* out = (float*)d_out;

  char* ws = (char*)d_ws;
  // workspace (peak ~100.2 MB):
  //   shb   @ 0        (32 MB)
  //   swb   @ 32 MB    (32 MB)  <- aliases offBT (dead before k_row writes swb)
  //   cvb   @ 64 MB    (32 MB)
  //   Bp    @ 96 MB    ( 4 MB)
  //   pf/sums/gate/bcomb after
  _Float16* shb   = (_Float16*)(ws + 0);
  _Float16* swb   = (_Float16*)(ws + 33554432);
  _Float16* offBT = (_Float16*)(ws + 33554432);   // alias of swb
  _Float16* cvb   = (_Float16*)(ws + 67108864);
  _Float16* Bp    = (_Float16*)(ws + 100663296);
  _Float16* pf    = (_Float16*)(ws + 104857600);
  float* sums     = (float*)(ws + 104988672);
  float* gate     = (float*)(ws + 105037824);
  float* bcomb    = (float*)(ws + 105086976);
  float* ssw = sums, *ssh = sums + 4096, *scv = sums + 8192;

  hipMemsetAsync(sums, 0, 3 * 4096 * sizeof(float), stream);
  k_toffB<<<8192, 256, 0, stream>>>(off, offBT);
  k_col<<<BB * WW2, 256, 0, stream>>>(x, offBT, shb, ssh);
  k_row<<<BB * HH, 256, 0, stream>>>(x, off, lw, swb, cvb, ssw, scv);
  k_gate<<<BB, 256, 0, stream>>>(ssw, ssh, scv, Ww, bw, Wh, bh, blc,
                                 fc1w, fc1b, fc2w, fc2b, gate);
  k_prep<<<BB * CC, 256, 0, stream>>>(gate, Ww, Wh, bw, bh, blc, Bp, bcomb);
  k_cvt<<<CC, 256, 0, stream>>>(pw, pf);
  k_gemm1<<<1024, 256, 0, stream>>>(swb, shb, Bp, bcomb, gate + 2 * BB * CC, cvb);
  k_gemm2<<<1024, 256, 0, stream>>>(cvb, pf, pb, out);
}